// Round 3
// baseline (1878.170 us; speedup 1.0000x reference)
//
#include <hip/hip_runtime.h>
#include <stdint.h>

typedef unsigned short u16;

#define B_   2
#define S_   2048
#define H_   4096
#define NH   32
#define NKV  8
#define HD   128
#define KVD  (NKV * HD)   // 1024
#define BS   (B_ * S_)    // 4096

typedef __bf16 bf16x8 __attribute__((ext_vector_type(8)));
typedef u16    u16x8  __attribute__((ext_vector_type(8)));
typedef u16    u16x4  __attribute__((ext_vector_type(4)));
typedef float  f32x4  __attribute__((ext_vector_type(4)));

__device__ __forceinline__ bf16x8 as_bf16x8(u16x8 v) { return __builtin_bit_cast(bf16x8, v); }

__device__ __forceinline__ float bf2f(u16 u) {
  union { uint32_t u; float f; } v; v.u = ((uint32_t)u) << 16; return v.f;
}
__device__ __forceinline__ u16 f2bf(float f) {
  union { float f; uint32_t u; } v; v.f = f;
  uint32_t r = v.u + 0x7FFFu + ((v.u >> 16) & 1u);
  return (u16)(r >> 16);
}

// ---------------------------------------------------------------------------
// Convert + transpose: fp32 in[R][C] -> bf16 out[C][R]; 64x64 tiles.
// grid.x = R/64, grid.y = C/64
// ---------------------------------------------------------------------------
__global__ __launch_bounds__(256) void conv_transpose_w(const float* __restrict__ in,
                                                        u16* __restrict__ out,
                                                        int ldi, int ldo) {
  __shared__ u16 tile[64][72];
  int r0 = blockIdx.x * 64, c0 = blockIdx.y * 64;
  int t = threadIdx.x;
  {
    int row = t >> 4, col = (t & 15) * 4;
#pragma unroll
    for (int rep = 0; rep < 4; ++rep) {
      int r = row + rep * 16;
      float4 v = *(const float4*)(in + (size_t)(r0 + r) * ldi + c0 + col);
      u16x4 h;
      h[0] = f2bf(v.x); h[1] = f2bf(v.y); h[2] = f2bf(v.z); h[3] = f2bf(v.w);
      *(u16x4*)&tile[r][col] = h;
    }
  }
  __syncthreads();
  {
    int row = t >> 2, c8 = (t & 3) * 8;
#pragma unroll
    for (int it = 0; it < 2; ++it) {
      int rr = c8 + it * 32;
      u16x8 v;
#pragma unroll
      for (int j = 0; j < 8; ++j) v[j] = tile[rr + j][row];
      *(u16x8*)(out + (size_t)(c0 + row) * ldo + r0 + rr) = v;
    }
  }
}

// ---------------------------------------------------------------------------
// V transpose (bf16): V[b*S_+s][kvh*HD+d] -> Vt[((b*NKV+kvh)*HD + d)*S_ + s]
// grid: (S_/64, HD/64, B_*NKV)
// ---------------------------------------------------------------------------
__global__ __launch_bounds__(256) void transpose_v(const u16* __restrict__ V,
                                                   u16* __restrict__ Vt) {
  __shared__ u16 tile[64][72];
  int g = blockIdx.z;
  const u16* in = V + (size_t)(g >> 3) * ((size_t)S_ * KVD) + (size_t)(g & 7) * HD;
  u16* out = Vt + (size_t)g * ((size_t)HD * S_);
  int r0 = blockIdx.x * 64, c0 = blockIdx.y * 64;
  int t = threadIdx.x;
  int row = t >> 2, c8 = (t & 3) * 8;
#pragma unroll
  for (int it = 0; it < 2; ++it) {
    int col = c8 + it * 32;
    *(u16x8*)&tile[row][col] = *(const u16x8*)(in + (size_t)(r0 + row) * KVD + c0 + col);
  }
  __syncthreads();
#pragma unroll
  for (int it = 0; it < 2; ++it) {
    int rr = c8 + it * 32;
    u16x8 v;
#pragma unroll
    for (int j = 0; j < 8; ++j) v[j] = tile[rr + j][row];
    *(u16x8*)(out + (size_t)(c0 + row) * S_ + r0 + rr) = v;
  }
}

// ---------------------------------------------------------------------------
// C[M][N] = A[M][K] @ Bt[N][K]^T.  A fp32 or bf16 (template), Bt bf16,
// C bf16 or fp32 (template).  128x128 block tile, 4 waves of 64x64.
// ---------------------------------------------------------------------------
template <bool A_F32, bool C_F32>
__global__ __launch_bounds__(256) void gemm_bt(const void* __restrict__ Ap,
                                               const u16* __restrict__ Bt,
                                               void* __restrict__ Cp,
                                               int M, int N, int K) {
  __shared__ u16 lsA[128][32];
  __shared__ u16 lsB[128][32];
  int t = threadIdx.x;
  int lane = t & 63;
  int w = t >> 6;
  int wm = (w >> 1) * 64, wn = (w & 1) * 64;
  int bm = blockIdx.x * 128, bn = blockIdx.y * 128;
  int fr = lane & 15, kq = lane >> 4;
  f32x4 acc[4][4] = {};

  for (int k0 = 0; k0 < K; k0 += 32) {
    if (A_F32) {
      const float* Af = (const float*)Ap;
      int row = t >> 3, col = (t & 7) * 4;
#pragma unroll
      for (int rep = 0; rep < 4; ++rep) {
        int r = row + rep * 32;
        float4 v = *(const float4*)(Af + (size_t)(bm + r) * K + k0 + col);
        u16x4 h;
        h[0] = f2bf(v.x); h[1] = f2bf(v.y); h[2] = f2bf(v.z); h[3] = f2bf(v.w);
        *(u16x4*)&lsA[r][col] = h;
      }
    } else {
      const u16* Ab = (const u16*)Ap;
#pragma unroll
      for (int rep = 0; rep < 2; ++rep) {
        int ch = rep * 256 + t;
        int row = ch >> 2, col = (ch & 3) * 8;
        *(u16x8*)&lsA[row][col] = *(const u16x8*)(Ab + (size_t)(bm + row) * K + k0 + col);
      }
    }
#pragma unroll
    for (int rep = 0; rep < 2; ++rep) {
      int ch = rep * 256 + t;
      int row = ch >> 2, col = (ch & 3) * 8;
      *(u16x8*)&lsB[row][col] = *(const u16x8*)(Bt + (size_t)(bn + row) * K + k0 + col);
    }
    __syncthreads();
    bf16x8 af[4], bfr[4];
#pragma unroll
    for (int i = 0; i < 4; ++i) af[i] = as_bf16x8(*(const u16x8*)&lsA[wm + i * 16 + fr][kq * 8]);
#pragma unroll
    for (int j = 0; j < 4; ++j) bfr[j] = as_bf16x8(*(const u16x8*)&lsB[wn + j * 16 + fr][kq * 8]);
#pragma unroll
    for (int i = 0; i < 4; ++i)
#pragma unroll
      for (int j = 0; j < 4; ++j)
        acc[i][j] = __builtin_amdgcn_mfma_f32_16x16x32_bf16(af[i], bfr[j], acc[i][j], 0, 0, 0);
    __syncthreads();
  }
#pragma unroll
  for (int i = 0; i < 4; ++i)
#pragma unroll
    for (int j = 0; j < 4; ++j)
#pragma unroll
      for (int r = 0; r < 4; ++r) {
        int row = bm + wm + i * 16 + kq * 4 + r;
        int col = bn + wn + j * 16 + fr;
        if (C_F32) ((float*)Cp)[(size_t)row * N + col] = acc[i][j][r];
        else       ((u16*)Cp)[(size_t)row * N + col] = f2bf(acc[i][j][r]);
      }
}

// ---------------------------------------------------------------------------
// RoPE in-place on bf16 Q [BS][H_] and K [BS][KVD].
// Positions are arange(S_) broadcast over batch (per reference setup).
// ---------------------------------------------------------------------------
__global__ __launch_bounds__(256) void rope_kernel(u16* __restrict__ Q,
                                                   u16* __restrict__ Kp) {
  int idx = blockIdx.x * 256 + threadIdx.x;  // BS * 40 * 64 total
  int j = idx & 63;
  int rem = idx >> 6;
  int hh = rem % 40;
  int tok = rem / 40;
  float p = (float)(tok % S_);
  float freq = __expf((float)j * (-9.210340371976184f / 64.0f));  // 10000^(-j/64)
  float sn, cs;
  __sincosf(p * freq, &sn, &cs);
  u16* base = (hh < NH) ? (Q + (size_t)tok * H_ + (size_t)hh * HD)
                        : (Kp + (size_t)tok * KVD + (size_t)(hh - NH) * HD);
  float x1 = bf2f(base[j]), x2 = bf2f(base[j + 64]);
  base[j]      = f2bf(x1 * cs - x2 * sn);
  base[j + 64] = f2bf(x2 * cs + x1 * sn);
}

// ---------------------------------------------------------------------------
// Flash attention, causal, GQA(4). grid: (S_/64, NH, B_), 4 waves/block,
// each wave owns 16 q-rows independently.
// ---------------------------------------------------------------------------
__global__ __launch_bounds__(256) void flash_attn(const u16* __restrict__ Q,
                                                  const u16* __restrict__ Kp,
                                                  const u16* __restrict__ Vt,
                                                  u16* __restrict__ O) {
  __shared__ u16 Plds[4][16][72];  // per-wave P tile (16q x 64kv), +8 pad
  int qt = blockIdx.x, h = blockIdx.y, b = blockIdx.z;
  int kvh = h >> 2;
  int t = threadIdx.x, lane = t & 63, w = t >> 6;
  int fr = lane & 15, kq = lane >> 4;
  int q0 = qt * 64 + w * 16;

  const u16* qbase = Q + (size_t)(b * S_ + q0 + fr) * H_ + (size_t)h * HD;
  bf16x8 qf[4];
#pragma unroll
  for (int kk = 0; kk < 4; ++kk) qf[kk] = as_bf16x8(*(const u16x8*)(qbase + kk * 32 + kq * 8));

  f32x4 o[8] = {};
  float mrow[4] = {-1e30f, -1e30f, -1e30f, -1e30f};
  float lrow[4] = {0.f, 0.f, 0.f, 0.f};

  const u16* kbase = Kp + (size_t)(b * S_) * KVD + (size_t)kvh * HD;
  const u16* vbase = Vt + (size_t)(b * NKV + kvh) * ((size_t)HD * S_);
  const float scale = 0.08838834764831845f;  // 1/sqrt(128)

  for (int k0 = 0; k0 <= q0 + 15; k0 += 64) {
    f32x4 s[4] = {};
#pragma unroll
    for (int kk = 0; kk < 4; ++kk) {
#pragma unroll
      for (int j = 0; j < 4; ++j) {
        bf16x8 kf = as_bf16x8(*(const u16x8*)(kbase + (size_t)(k0 + j * 16 + fr) * KVD + kk * 32 + kq * 8));
        s[j] = __builtin_amdgcn_mfma_f32_16x16x32_bf16(qf[kk], kf, s[j], 0, 0, 0);
      }
    }
    // scale + causal mask + row max
    float mt[4] = {-1e30f, -1e30f, -1e30f, -1e30f};
#pragma unroll
    for (int j = 0; j < 4; ++j) {
      int kv = k0 + j * 16 + fr;
#pragma unroll
      for (int r = 0; r < 4; ++r) {
        int qr = q0 + kq * 4 + r;
        float sv = (kv <= qr) ? s[j][r] * scale : -1e30f;
        s[j][r] = sv;
        mt[r] = fmaxf(mt[r], sv);
      }
    }
#pragma unroll
    for (int off = 1; off < 16; off <<= 1)
#pragma unroll
      for (int r = 0; r < 4; ++r) mt[r] = fmaxf(mt[r], __shfl_xor(mt[r], off, 64));

    float alpha[4], lt[4];
#pragma unroll
    for (int r = 0; r < 4; ++r) {
      float mn = fmaxf(mrow[r], mt[r]);
      alpha[r] = __expf(mrow[r] - mn);
      mrow[r] = mn;
      lt[r] = 0.f;
    }
#pragma unroll
    for (int j = 0; j < 4; ++j)
#pragma unroll
      for (int r = 0; r < 4; ++r) {
        float p = __expf(s[j][r] - mrow[r]);
        s[j][r] = p;
        lt[r] += p;
      }
#pragma unroll
    for (int off = 1; off < 16; off <<= 1)
#pragma unroll
      for (int r = 0; r < 4; ++r) lt[r] += __shfl_xor(lt[r], off, 64);
#pragma unroll
    for (int r = 0; r < 4; ++r) lrow[r] = lrow[r] * alpha[r] + lt[r];
#pragma unroll
    for (int tt = 0; tt < 8; ++tt)
#pragma unroll
      for (int r = 0; r < 4; ++r) o[tt][r] *= alpha[r];

    // P (C-layout) -> LDS -> A-layout frags (same-type u16 accesses).
#pragma unroll
    for (int j = 0; j < 4; ++j)
#pragma unroll
      for (int r = 0; r < 4; ++r)
        Plds[w][kq * 4 + r][j * 16 + fr] = f2bf(s[j][r]);

#pragma unroll
    for (int st = 0; st < 2; ++st) {
      bf16x8 pf = as_bf16x8(*(const u16x8*)&Plds[w][fr][st * 32 + kq * 8]);
#pragma unroll
      for (int tt = 0; tt < 8; ++tt) {
        bf16x8 vf = as_bf16x8(*(const u16x8*)(vbase + (size_t)(tt * 16 + fr) * S_ + k0 + st * 32 + kq * 8));
        o[tt] = __builtin_amdgcn_mfma_f32_16x16x32_bf16(pf, vf, o[tt], 0, 0, 0);
      }
    }
  }

  float inv[4];
#pragma unroll
  for (int r = 0; r < 4; ++r) inv[r] = 1.0f / lrow[r];
  u16* obase = O + (size_t)(b * S_ + q0) * H_ + (size_t)h * HD;
#pragma unroll
  for (int tt = 0; tt < 8; ++tt)
#pragma unroll
    for (int r = 0; r < 4; ++r)
      obase[(size_t)(kq * 4 + r) * H_ + tt * 16 + fr] = f2bf(o[tt][r] * inv[r]);
}

// ---------------------------------------------------------------------------
extern "C" void kernel_launch(void* const* d_in, const int* in_sizes, int n_in,
                              void* d_out, int out_size, void* d_ws, size_t ws_size,
                              hipStream_t stream) {
  const float* X  = (const float*)d_in[0];
  const float* Wq = (const float*)d_in[2];
  const float* Wk = (const float*)d_in[3];
  const float* Wv = (const float*)d_in[4];
  const float* Wo = (const float*)d_in[5];
  float* out = (float*)d_out;

  // ws (80 MiB): K 8 | Vt 8 | O 32 | Wt 32   (bf16)
  char* ws = (char*)d_ws;
  u16* Kb = (u16*)ws;
  u16* Vt = (u16*)(ws + 8ull  * 1024 * 1024);
  u16* Ob = (u16*)(ws + 16ull * 1024 * 1024);
  u16* Wt = (u16*)(ws + 48ull * 1024 * 1024);
  // d_out is 64 MiB fp32; park bf16 Q (32 MiB) and pre-transpose V (8 MiB)
  // there — both dead before the final GEMM overwrites all of d_out.
  u16* Qb = (u16*)d_out;
  u16* Vb = (u16*)((char*)d_out + 32ull * 1024 * 1024);

  dim3 blk(256);

  // Q = X @ Wq
  conv_transpose_w<<<dim3(64, 64), blk, 0, stream>>>(Wq, Wt, H_, H_);
  gemm_bt<true, false><<<dim3(32, 32), blk, 0, stream>>>(X, Wt, Qb, BS, H_, H_);
  // K = X @ Wk
  conv_transpose_w<<<dim3(64, 16), blk, 0, stream>>>(Wk, Wt, KVD, H_);
  gemm_bt<true, false><<<dim3(32, 8), blk, 0, stream>>>(X, Wt, Kb, BS, KVD, H_);
  // V = X @ Wv
  conv_transpose_w<<<dim3(64, 16), blk, 0, stream>>>(Wv, Wt, KVD, H_);
  gemm_bt<true, false><<<dim3(32, 8), blk, 0, stream>>>(X, Wt, Vb, BS, KVD, H_);
  // RoPE in-place on Q and K
  rope_kernel<<<dim3((BS * 40 * 64) / 256), blk, 0, stream>>>(Qb, Kb);
  // V -> Vt
  transpose_v<<<dim3(S_ / 64, HD / 64, B_ * NKV), blk, 0, stream>>>(Vb, Vt);
  // attention -> Ob
  flash_attn<<<dim3(S_ / 64, NH, B_), blk, 0, stream>>>(Qb, Kb, Vt, Ob);
  // out = Ob @ Wo  (fp32 out, overwrites all of d_out)
  conv_transpose_w<<<dim3(64, 64), blk, 0, stream>>>(Wo, Wt, H_, H_);
  gemm_bt<false, true><<<dim3(32, 32), blk, 0, stream>>>(Ob, Wt, out, BS, H_, H_);
}

// Round 4
// 1354.157 us; speedup vs baseline: 1.3870x; 1.3870x over previous
//
#include <hip/hip_runtime.h>
#include <stdint.h>

typedef unsigned short u16;

#define B_   2
#define S_   2048
#define H_   4096
#define NH   32
#define NKV  8
#define HD   128
#define KVD  (NKV * HD)   // 1024
#define BS   (B_ * S_)    // 4096

typedef __bf16 bf16x8 __attribute__((ext_vector_type(8)));
typedef u16    u16x8  __attribute__((ext_vector_type(8)));
typedef u16    u16x4  __attribute__((ext_vector_type(4)));
typedef float  f32x4  __attribute__((ext_vector_type(4)));

__device__ __forceinline__ bf16x8 as_bf16x8(u16x8 v) { return __builtin_bit_cast(bf16x8, v); }

__device__ __forceinline__ float bf2f(u16 u) {
  union { uint32_t u; float f; } v; v.u = ((uint32_t)u) << 16; return v.f;
}
__device__ __forceinline__ u16 f2bf(float f) {
  union { float f; uint32_t u; } v; v.f = f;
  uint32_t r = v.u + 0x7FFFu + ((v.u >> 16) & 1u);
  return (u16)(r >> 16);
}

// ---------------------------------------------------------------------------
// Convert + transpose: fp32 in[R][C] -> bf16 out[C][R]; 64x64 tiles.
// ---------------------------------------------------------------------------
__global__ __launch_bounds__(256) void conv_transpose_w(const float* __restrict__ in,
                                                        u16* __restrict__ out,
                                                        int ldi, int ldo) {
  __shared__ u16 tile[64][72];
  int r0 = blockIdx.x * 64, c0 = blockIdx.y * 64;
  int t = threadIdx.x;
  {
    int row = t >> 4, col = (t & 15) * 4;
#pragma unroll
    for (int rep = 0; rep < 4; ++rep) {
      int r = row + rep * 16;
      float4 v = *(const float4*)(in + (size_t)(r0 + r) * ldi + c0 + col);
      u16x4 h;
      h[0] = f2bf(v.x); h[1] = f2bf(v.y); h[2] = f2bf(v.z); h[3] = f2bf(v.w);
      *(u16x4*)&tile[r][col] = h;
    }
  }
  __syncthreads();
  {
    int row = t >> 2, c8 = (t & 3) * 8;
#pragma unroll
    for (int it = 0; it < 2; ++it) {
      int rr = c8 + it * 32;
      u16x8 v;
#pragma unroll
      for (int j = 0; j < 8; ++j) v[j] = tile[rr + j][row];
      *(u16x8*)(out + (size_t)(c0 + row) * ldo + r0 + rr) = v;
    }
  }
}

// ---------------------------------------------------------------------------
// V transpose (bf16): V[b*S_+s][kvh*HD+d] -> Vt[((b*NKV+kvh)*HD + d)*S_ + s]
// ---------------------------------------------------------------------------
__global__ __launch_bounds__(256) void transpose_v(const u16* __restrict__ V,
                                                   u16* __restrict__ Vt) {
  __shared__ u16 tile[64][72];
  int g = blockIdx.z;
  const u16* in = V + (size_t)(g >> 3) * ((size_t)S_ * KVD) + (size_t)(g & 7) * HD;
  u16* out = Vt + (size_t)g * ((size_t)HD * S_);
  int r0 = blockIdx.x * 64, c0 = blockIdx.y * 64;
  int t = threadIdx.x;
  int row = t >> 2, c8 = (t & 3) * 8;
#pragma unroll
  for (int it = 0; it < 2; ++it) {
    int col = c8 + it * 32;
    *(u16x8*)&tile[row][col] = *(const u16x8*)(in + (size_t)(r0 + row) * KVD + c0 + col);
  }
  __syncthreads();
#pragma unroll
  for (int it = 0; it < 2; ++it) {
    int rr = c8 + it * 32;
    u16x8 v;
#pragma unroll
    for (int j = 0; j < 8; ++j) v[j] = tile[rr + j][row];
    *(u16x8*)(out + (size_t)(c0 + row) * S_ + r0 + rr) = v;
  }
}

// ---------------------------------------------------------------------------
// C[M][N] = A[M][K] @ Bt[N][K]^T.  A fp32 or bf16, C bf16 or fp32.
// 128x128 block tile, 4 waves of 64x64.
// ---------------------------------------------------------------------------
template <bool A_F32, bool C_F32>
__global__ __launch_bounds__(256) void gemm_bt(const void* __restrict__ Ap,
                                               const u16* __restrict__ Bt,
                                               void* __restrict__ Cp,
                                               int M, int N, int K) {
  __shared__ u16 lsA[128][32];
  __shared__ u16 lsB[128][32];
  int t = threadIdx.x;
  int lane = t & 63;
  int w = t >> 6;
  int wm = (w >> 1) * 64, wn = (w & 1) * 64;
  int bm = blockIdx.x * 128, bn = blockIdx.y * 128;
  int fr = lane & 15, kq = lane >> 4;
  f32x4 acc[4][4] = {};

  for (int k0 = 0; k0 < K; k0 += 32) {
    if (A_F32) {
      const float* Af = (const float*)Ap;
      int row = t >> 3, col = (t & 7) * 4;
#pragma unroll
      for (int rep = 0; rep < 4; ++rep) {
        int r = row + rep * 32;
        float4 v = *(const float4*)(Af + (size_t)(bm + r) * K + k0 + col);
        u16x4 h;
        h[0] = f2bf(v.x); h[1] = f2bf(v.y); h[2] = f2bf(v.z); h[3] = f2bf(v.w);
        *(u16x4*)&lsA[r][col] = h;
      }
    } else {
      const u16* Ab = (const u16*)Ap;
#pragma unroll
      for (int rep = 0; rep < 2; ++rep) {
        int ch = rep * 256 + t;
        int row = ch >> 2, col = (ch & 3) * 8;
        *(u16x8*)&lsA[row][col] = *(const u16x8*)(Ab + (size_t)(bm + row) * K + k0 + col);
      }
    }
#pragma unroll
    for (int rep = 0; rep < 2; ++rep) {
      int ch = rep * 256 + t;
      int row = ch >> 2, col = (ch & 3) * 8;
      *(u16x8*)&lsB[row][col] = *(const u16x8*)(Bt + (size_t)(bn + row) * K + k0 + col);
    }
    __syncthreads();
    bf16x8 af[4], bfr[4];
#pragma unroll
    for (int i = 0; i < 4; ++i) af[i] = as_bf16x8(*(const u16x8*)&lsA[wm + i * 16 + fr][kq * 8]);
#pragma unroll
    for (int j = 0; j < 4; ++j) bfr[j] = as_bf16x8(*(const u16x8*)&lsB[wn + j * 16 + fr][kq * 8]);
#pragma unroll
    for (int i = 0; i < 4; ++i)
#pragma unroll
      for (int j = 0; j < 4; ++j)
        acc[i][j] = __builtin_amdgcn_mfma_f32_16x16x32_bf16(af[i], bfr[j], acc[i][j], 0, 0, 0);
    __syncthreads();
  }
#pragma unroll
  for (int i = 0; i < 4; ++i)
#pragma unroll
    for (int j = 0; j < 4; ++j)
#pragma unroll
      for (int r = 0; r < 4; ++r) {
        int row = bm + wm + i * 16 + kq * 4 + r;
        int col = bn + wn + j * 16 + fr;
        if (C_F32) ((float*)Cp)[(size_t)row * N + col] = acc[i][j][r];
        else       ((u16*)Cp)[(size_t)row * N + col] = f2bf(acc[i][j][r]);
      }
}

// ---------------------------------------------------------------------------
// RoPE in-place on bf16 Q [BS][H_] and K [BS][KVD].
// ---------------------------------------------------------------------------
__global__ __launch_bounds__(256) void rope_kernel(u16* __restrict__ Q,
                                                   u16* __restrict__ Kp) {
  int idx = blockIdx.x * 256 + threadIdx.x;  // BS * 40 * 64 total
  int j = idx & 63;
  int rem = idx >> 6;
  int hh = rem % 40;
  int tok = rem / 40;
  float p = (float)(tok % S_);
  float freq = __expf((float)j * (-9.210340371976184f / 64.0f));  // 10000^(-j/64)
  float sn, cs;
  __sincosf(p * freq, &sn, &cs);
  u16* base = (hh < NH) ? (Q + (size_t)tok * H_ + (size_t)hh * HD)
                        : (Kp + (size_t)tok * KVD + (size_t)(hh - NH) * HD);
  float x1 = bf2f(base[j]), x2 = bf2f(base[j + 64]);
  base[j]      = f2bf(x1 * cs - x2 * sn);
  base[j + 64] = f2bf(x2 * cs + x1 * sn);
}

// ---------------------------------------------------------------------------
// Flash attention, causal, GQA(4).
// grid: (S_/16, NKV, B_).  Block = 4 waves = the 4 heads of one GQA group,
// each wave owns the SAME 16 q-rows for its head; K/V tiles staged in LDS
// once per iteration, shared by all 4 waves (4x traffic cut vs per-wave).
// K tile: xor-swizzle at 16B granularity (conflict-free-ish b128 reads).
// V tile: xor-swizzle at 8B granularity, read as b64 pairs (~4-way).
// ---------------------------------------------------------------------------
__global__ __launch_bounds__(256) void flash_attn(const u16* __restrict__ Q,
                                                  const u16* __restrict__ Kp,
                                                  const u16* __restrict__ Vt,
                                                  u16* __restrict__ O) {
  __shared__ __align__(16) u16 Ks[64 * 128];   // [kv 64][d 128], swizzled
  __shared__ __align__(16) u16 Vs[128 * 64];   // [d 128][kv 64], swizzled
  __shared__ u16 Plds[4][16][72];              // per-wave P tile, +8 pad
  int qt = blockIdx.x, kvh = blockIdx.y, b = blockIdx.z;
  int t = threadIdx.x, lane = t & 63, w = t >> 6;
  int h = kvh * 4 + w;                         // this wave's head
  int fr = lane & 15, kq = lane >> 4;
  int q0 = qt * 16;

  const u16* qbase = Q + (size_t)(b * S_ + q0 + fr) * H_ + (size_t)h * HD;
  bf16x8 qf[4];
#pragma unroll
  for (int kk = 0; kk < 4; ++kk) qf[kk] = as_bf16x8(*(const u16x8*)(qbase + kk * 32 + kq * 8));

  f32x4 o[8] = {};
  float mrow[4] = {-1e30f, -1e30f, -1e30f, -1e30f};
  float lrow[4] = {0.f, 0.f, 0.f, 0.f};

  const u16* kbase = Kp + (size_t)(b * S_) * KVD + (size_t)kvh * HD;
  const u16* vbase = Vt + (size_t)(b * NKV + kvh) * ((size_t)HD * S_);
  const float scale = 0.08838834764831845f;  // 1/sqrt(128)

  int niter = (q0 + 15) / 64 + 1;
  for (int kt = 0; kt < niter; ++kt) {
    int k0 = kt * 64;
    if (kt) __syncthreads();
    // ---- stage K tile: 64 rows x 256B, 16B chunks, chunk' = c ^ (row&15)
#pragma unroll
    for (int ps = 0; ps < 4; ++ps) {
      int idx = ps * 256 + t;
      int row = idx >> 4, c = idx & 15;
      *(u16x8*)&Ks[row * 128 + ((c ^ row) & 15) * 8] =
          *(const u16x8*)(kbase + (size_t)(k0 + row) * KVD + c * 8);
    }
    // ---- stage V tile: 128 rows x 128B, 8B subchunks, sub' = s ^ (row&15)
#pragma unroll
    for (int ps = 0; ps < 4; ++ps) {
      int idx = ps * 256 + t;
      int row = idx >> 3, c = idx & 7;
      u16x8 v = *(const u16x8*)(vbase + (size_t)row * S_ + k0 + c * 8);
      u16x4 lo, hi;
#pragma unroll
      for (int i = 0; i < 4; ++i) { lo[i] = v[i]; hi[i] = v[4 + i]; }
      *(u16x4*)&Vs[row * 64 + (((2 * c) ^ (row & 15)) * 4)] = lo;
      *(u16x4*)&Vs[row * 64 + (((2 * c + 1) ^ (row & 15)) * 4)] = hi;
    }
    __syncthreads();

    // ---- S = Q K^T from LDS
    f32x4 s[4] = {};
#pragma unroll
    for (int kk = 0; kk < 4; ++kk) {
#pragma unroll
      for (int j = 0; j < 4; ++j) {
        bf16x8 kf = as_bf16x8(*(const u16x8*)&Ks[(j * 16 + fr) * 128 + (((kk * 4 + kq) ^ fr) & 15) * 8]);
        s[j] = __builtin_amdgcn_mfma_f32_16x16x32_bf16(qf[kk], kf, s[j], 0, 0, 0);
      }
    }
    // ---- scale + causal mask + row max
    float mt[4] = {-1e30f, -1e30f, -1e30f, -1e30f};
#pragma unroll
    for (int j = 0; j < 4; ++j) {
      int kv = k0 + j * 16 + fr;
#pragma unroll
      for (int r = 0; r < 4; ++r) {
        int qr = q0 + kq * 4 + r;
        float sv = (kv <= qr) ? s[j][r] * scale : -1e30f;
        s[j][r] = sv;
        mt[r] = fmaxf(mt[r], sv);
      }
    }
#pragma unroll
    for (int off = 1; off < 16; off <<= 1)
#pragma unroll
      for (int r = 0; r < 4; ++r) mt[r] = fmaxf(mt[r], __shfl_xor(mt[r], off, 64));

    float alpha[4], lt[4];
#pragma unroll
    for (int r = 0; r < 4; ++r) {
      float mn = fmaxf(mrow[r], mt[r]);
      alpha[r] = __expf(mrow[r] - mn);
      mrow[r] = mn;
      lt[r] = 0.f;
    }
#pragma unroll
    for (int j = 0; j < 4; ++j)
#pragma unroll
      for (int r = 0; r < 4; ++r) {
        float p = __expf(s[j][r] - mrow[r]);
        s[j][r] = p;
        lt[r] += p;
      }
#pragma unroll
    for (int off = 1; off < 16; off <<= 1)
#pragma unroll
      for (int r = 0; r < 4; ++r) lt[r] += __shfl_xor(lt[r], off, 64);
#pragma unroll
    for (int r = 0; r < 4; ++r) lrow[r] = lrow[r] * alpha[r] + lt[r];
#pragma unroll
    for (int tt = 0; tt < 8; ++tt)
#pragma unroll
      for (int r = 0; r < 4; ++r) o[tt][r] *= alpha[r];

    // ---- P (C-layout) -> per-wave LDS -> A-layout frags
#pragma unroll
    for (int j = 0; j < 4; ++j)
#pragma unroll
      for (int r = 0; r < 4; ++r)
        Plds[w][kq * 4 + r][j * 16 + fr] = f2bf(s[j][r]);

#pragma unroll
    for (int st = 0; st < 2; ++st) {
      bf16x8 pf = as_bf16x8(*(const u16x8*)&Plds[w][fr][st * 32 + kq * 8]);
#pragma unroll
      for (int tt = 0; tt < 8; ++tt) {
        int rr = tt * 16 + fr;
        int s0 = ((st * 8 + kq * 2) ^ (fr & 15)) * 4;
        int s1 = ((st * 8 + kq * 2 + 1) ^ (fr & 15)) * 4;
        u16x4 lo = *(const u16x4*)&Vs[rr * 64 + s0];
        u16x4 hi = *(const u16x4*)&Vs[rr * 64 + s1];
        u16x8 vv;
#pragma unroll
        for (int i = 0; i < 4; ++i) { vv[i] = lo[i]; vv[4 + i] = hi[i]; }
        o[tt] = __builtin_amdgcn_mfma_f32_16x16x32_bf16(pf, as_bf16x8(vv), o[tt], 0, 0, 0);
      }
    }
  }

  float inv[4];
#pragma unroll
  for (int r = 0; r < 4; ++r) inv[r] = 1.0f / lrow[r];
  u16* obase = O + (size_t)(b * S_ + q0) * H_ + (size_t)h * HD;
#pragma unroll
  for (int tt = 0; tt < 8; ++tt)
#pragma unroll
    for (int r = 0; r < 4; ++r)
      obase[(size_t)(kq * 4 + r) * H_ + tt * 16 + fr] = f2bf(o[tt][r] * inv[r]);
}

// ---------------------------------------------------------------------------
extern "C" void kernel_launch(void* const* d_in, const int* in_sizes, int n_in,
                              void* d_out, int out_size, void* d_ws, size_t ws_size,
                              hipStream_t stream) {
  const float* X  = (const float*)d_in[0];
  const float* Wq = (const float*)d_in[2];
  const float* Wk = (const float*)d_in[3];
  const float* Wv = (const float*)d_in[4];
  const float* Wo = (const float*)d_in[5];
  float* out = (float*)d_out;

  // ws (80 MiB): K 8 | Vt 8 | O 32 | Wt 32   (bf16)
  char* ws = (char*)d_ws;
  u16* Kb = (u16*)ws;
  u16* Vt = (u16*)(ws + 8ull  * 1024 * 1024);
  u16* Ob = (u16*)(ws + 16ull * 1024 * 1024);
  u16* Wt = (u16*)(ws + 48ull * 1024 * 1024);
  // d_out is 64 MiB fp32; park bf16 Q (32 MiB) and pre-transpose V (8 MiB)
  // there — both dead before the final GEMM overwrites all of d_out.
  u16* Qb = (u16*)d_out;
  u16* Vb = (u16*)((char*)d_out + 32ull * 1024 * 1024);

  dim3 blk(256);

  // Q = X @ Wq
  conv_transpose_w<<<dim3(64, 64), blk, 0, stream>>>(Wq, Wt, H_, H_);
  gemm_bt<true, false><<<dim3(32, 32), blk, 0, stream>>>(X, Wt, Qb, BS, H_, H_);
  // K = X @ Wk
  conv_transpose_w<<<dim3(64, 16), blk, 0, stream>>>(Wk, Wt, KVD, H_);
  gemm_bt<true, false><<<dim3(32, 8), blk, 0, stream>>>(X, Wt, Kb, BS, KVD, H_);
  // V = X @ Wv
  conv_transpose_w<<<dim3(64, 16), blk, 0, stream>>>(Wv, Wt, KVD, H_);
  gemm_bt<true, false><<<dim3(32, 8), blk, 0, stream>>>(X, Wt, Vb, BS, KVD, H_);
  // RoPE in-place on Q and K
  rope_kernel<<<dim3((BS * 40 * 64) / 256), blk, 0, stream>>>(Qb, Kb);
  // V -> Vt
  transpose_v<<<dim3(S_ / 64, HD / 64, B_ * NKV), blk, 0, stream>>>(Vb, Vt);
  // attention -> Ob
  flash_attn<<<dim3(S_ / 16, NKV, B_), blk, 0, stream>>>(Qb, Kb, Vt, Ob);
  // out = Ob @ Wo  (fp32 out, overwrites all of d_out)
  conv_transpose_w<<<dim3(64, 64), blk, 0, stream>>>(Wo, Wt, H_, H_);
  gemm_bt<false, true><<<dim3(32, 32), blk, 0, stream>>>(Ob, Wt, out, BS, H_, H_);
}